// Round 3
// baseline (388.021 us; speedup 1.0000x reference)
//
#include <hip/hip_runtime.h>
#include <cstdint>
#include <cstddef>

#define DEVI __device__ __forceinline__

typedef __attribute__((ext_vector_type(8))) short short8;
typedef __attribute__((ext_vector_type(4))) float f32x4;

static constexpr int Bdim = 2, T = 2048, C = 2048, H = 16, D = 128;
static constexpr int CQ = 3 * C; // 6144

DEVI unsigned short f2bf(float f) {
  unsigned int u = __float_as_uint(f);
  u = (u + 0x7fffu + ((u >> 16) & 1u)) >> 16; // RNE
  return (unsigned short)u;
}
DEVI float bf2f(unsigned int u) { return __uint_as_float(u << 16); }

DEVI void gload_lds16(const void* g, void* l) {
  __builtin_amdgcn_global_load_lds((const __attribute__((address_space(1))) void*)g,
                                   (__attribute__((address_space(3))) void*)l, 16, 0, 0);
}

// ---------------- f32 -> bf16 convert (4 elems/thread) ----------------
__global__ __launch_bounds__(256) void convert_bf16(const float* __restrict__ src,
                                                    unsigned short* __restrict__ dst, int n) {
  const int i = (blockIdx.x * 256 + threadIdx.x) * 4;
  if (i >= n) return;
  float4 v = *(const float4*)&src[i];
  uint2 o;
  o.x = (unsigned)f2bf(v.x) | ((unsigned)f2bf(v.y) << 16);
  o.y = (unsigned)f2bf(v.z) | ((unsigned)f2bf(v.w) << 16);
  *(uint2*)&dst[i] = o;
}

// ---------------- bf16 GEMM, B^T input ----------------
template <int OUT_BF16>
__global__ __launch_bounds__(256) void gemm_bt(const unsigned short* __restrict__ A,
                                               const unsigned short* __restrict__ Bm,
                                               void* __restrict__ outp,
                                               int M, int N, int Kd) {
  __shared__ __align__(16) unsigned short lds_a[128 * 32];
  __shared__ __align__(16) unsigned short lds_b[128 * 32];
  const int tid = threadIdx.x;
  const int wid = tid >> 6, lane = tid & 63;
  const int lg = lane >> 4, lc = lane & 15;
  const int m0 = blockIdx.y * 128, n0 = blockIdx.x * 128;
  const int wr = (wid >> 1) * 64, wc = (wid & 1) * 64;
  const int srow = lane >> 2;
  const int scol = (lane & 3) * 8;

  f32x4 acc[4][4] = {};

  for (int k0 = 0; k0 < Kd; k0 += 32) {
    __syncthreads();
#pragma unroll
    for (int i = 0; i < 2; ++i) {
      const int c = wid * 2 + i;
      const int row = c * 16 + srow;
      gload_lds16(&A[(size_t)(m0 + row) * Kd + k0 + scol], &lds_a[c * 512]);
      gload_lds16(&Bm[(size_t)(n0 + row) * Kd + k0 + scol], &lds_b[c * 512]);
    }
    __syncthreads();
    short8 af[4], bf[4];
#pragma unroll
    for (int m = 0; m < 4; ++m)
      af[m] = *(const short8*)&lds_a[(wr + m * 16 + lc) * 32 + lg * 8];
#pragma unroll
    for (int n = 0; n < 4; ++n)
      bf[n] = *(const short8*)&lds_b[(wc + n * 16 + lc) * 32 + lg * 8];
#pragma unroll
    for (int m = 0; m < 4; ++m)
#pragma unroll
      for (int n = 0; n < 4; ++n)
        acc[m][n] = __builtin_amdgcn_mfma_f32_16x16x32_bf16(af[m], bf[n], acc[m][n], 0, 0, 0);
  }

#pragma unroll
  for (int m = 0; m < 4; ++m)
#pragma unroll
    for (int n = 0; n < 4; ++n)
#pragma unroll
      for (int r = 0; r < 4; ++r) {
        const int row = m0 + wr + m * 16 + lg * 4 + r;
        const int col = n0 + wc + n * 16 + lc;
        const float v = acc[m][n][r];
        if (OUT_BF16)
          ((unsigned short*)outp)[(size_t)row * N + col] = f2bf(v);
        else
          ((float*)outp)[(size_t)row * N + col] = v;
      }
}

// ---------------- RoPE ----------------
__global__ __launch_bounds__(256) void rope_kernel(const unsigned short* __restrict__ qkv,
                                                   const float* __restrict__ cosb,
                                                   const float* __restrict__ sinb,
                                                   unsigned short* __restrict__ Qr,
                                                   unsigned short* __restrict__ Kr) {
  const int idx = blockIdx.x * 256 + threadIdx.x;
  const int i = idx & 63;
  const int h = (idx >> 6) & (H - 1);
  const int tg = idx >> 10;
  const int t = tg & (T - 1);
  const int b = tg >> 11;
  const float c = cosb[t * 64 + i], s = sinb[t * 64 + i];
  const unsigned short* row = qkv + (size_t)tg * CQ;
  const unsigned int q = *(const unsigned int*)&row[h * D + 2 * i];
  const unsigned int k = *(const unsigned int*)&row[C + h * D + 2 * i];
  const float q0 = bf2f(q & 0xffffu), q1 = bf2f(q >> 16);
  const float k0 = bf2f(k & 0xffffu), k1 = bf2f(k >> 16);
  const float SC = 0.08838834764831845f; // 1/sqrt(128)
  const float q0r = (q0 * c - q1 * s) * SC, q1r = (q0 * s + q1 * c) * SC;
  const float k0r = k0 * c - k1 * s, k1r = k0 * s + k1 * c;
  const size_t off = ((size_t)(b * H + h) * T + t) * D + 2 * i;
  *(unsigned int*)&Qr[off] = (unsigned)f2bf(q0r) | ((unsigned)f2bf(q1r) << 16);
  *(unsigned int*)&Kr[off] = (unsigned)f2bf(k0r) | ((unsigned)f2bf(k1r) << 16);
}

// ---------------- V transpose ----------------
__global__ __launch_bounds__(256) void transpose_v(const unsigned short* __restrict__ qkv,
                                                   unsigned short* __restrict__ Vt) {
  __shared__ unsigned short tile[64][65];
  const int bh = blockIdx.z, b = bh >> 4, h = bh & (H - 1);
  const int t0 = blockIdx.x * 64, d0 = blockIdx.y * 64;
  const int tx = threadIdx.x & 63, ty = threadIdx.x >> 6;
#pragma unroll
  for (int rr = 0; rr < 64; rr += 4)
    tile[rr + ty][tx] = qkv[(size_t)(b * T + t0 + rr + ty) * CQ + 2 * C + h * D + d0 + tx];
  __syncthreads();
#pragma unroll
  for (int rr = 0; rr < 64; rr += 4)
    Vt[((size_t)bh * D + d0 + rr + ty) * T + t0 + tx] = tile[tx][rr + ty];
}

// ---------------- causal flash attention, pipelined ----------------
// grid (T/128, B*H), 4 waves; wave owns 32 q rows. KV tile = 64.
// K double-buffered, V single-buffered; raw s_barrier + counted vmcnt(4)
// so prefetch loads stay in flight across barriers (T3/T4-lite).
__global__ __launch_bounds__(256, 2) void flash_attn(const unsigned short* __restrict__ Q,
                                                     const unsigned short* __restrict__ K,
                                                     const unsigned short* __restrict__ Vt,
                                                     unsigned short* __restrict__ Y) {
  __shared__ __align__(16) unsigned short ldsK[2][64 * 128];  // 32 KB
  __shared__ __align__(16) unsigned short ldsV[128 * 64];     // 16 KB
  __shared__ __align__(16) unsigned short p_lds[4][32][72];   // 18 KB

  const int bh = blockIdx.y;
  const int qt = gridDim.x - 1 - blockIdx.x;  // heavy blocks first (LPT)
  const int wid = threadIdx.x >> 6;
  const int lane = threadIdx.x & 63;
  const int lg = lane >> 4, lc = lane & 15;
  const int b = bh >> 4, h = bh & (H - 1);
  const int qb = qt * 128 + wid * 32;

  const unsigned short* Qh = Q + (size_t)bh * T * D;
  const unsigned short* Kh = K + (size_t)bh * T * D;
  const unsigned short* Vh = Vt + (size_t)bh * D * T;

  // staging geometry (per wave: 4 K-loads, 4 V-loads)
  const int k_row_in = lane >> 4;             // 0..3
  const int k_cc_x = lane & 15;               // ^ (row&7)
  const int v_row_in = lane >> 3;             // 0..7
  const int v_cc_x = lane & 7;

  short8 qf[2][4];
#pragma unroll
  for (int m = 0; m < 2; ++m)
#pragma unroll
    for (int kc = 0; kc < 4; ++kc)
      qf[m][kc] = *(const short8*)&Qh[(size_t)(qb + m * 16 + lc) * D + kc * 32 + lg * 8];

  // ---- prologue: issue K(0) then V(0) ----
#pragma unroll
  for (int j = 0; j < 4; ++j) {
    const int r0 = (wid * 4 + j) * 4;
    const int row = r0 + k_row_in;
    const int cc = k_cc_x ^ (row & 7);
    gload_lds16(&Kh[(size_t)row * D + cc * 8], &ldsK[0][r0 * 128]);
  }
#pragma unroll
  for (int j = 0; j < 4; ++j) {
    const int r0 = (wid * 4 + j) * 8;
    const int row = r0 + v_row_in;
    const int cc = v_cc_x ^ (row & 7);
    gload_lds16(&Vh[(size_t)row * T + cc * 8], &ldsV[r0 * 64]);
  }

  f32x4 oacc[2][8] = {};
  float m_run[2][4], l_run[2][4];
#pragma unroll
  for (int m = 0; m < 2; ++m)
#pragma unroll
    for (int r = 0; r < 4; ++r) { m_run[m][r] = -1e30f; l_run[m][r] = 0.f; }

  int cur = 0;
  const int ntb = 2 * qt + 2;
  for (int t = 0; t < ntb; ++t) {
    const int kv0 = t * 64;
    const int kvn = (kv0 + 64 < T - 64) ? kv0 + 64 : T - 64;  // clamped prefetch base
    const bool active = (kv0 <= qb + 31);

    // ---- barrier 1: K(t) landed (4 newest = V(t) may stay in flight) ----
    asm volatile("s_waitcnt vmcnt(4)" ::: "memory");
    __builtin_amdgcn_s_barrier();
    __builtin_amdgcn_sched_barrier(0);

    // ---- QK^T(t) ----
    f32x4 s[2][4] = {};
    if (active) {
      __builtin_amdgcn_s_setprio(1);
#pragma unroll
      for (int ss = 0; ss < 4; ++ss) {
        const int row = ss * 16 + lc;
#pragma unroll
        for (int kc = 0; kc < 4; ++kc) {
          const int p = (kc * 4 + lg) ^ (lc & 7);
          short8 kf = *(const short8*)&ldsK[cur][row * 128 + p * 8];
          s[0][ss] = __builtin_amdgcn_mfma_f32_16x16x32_bf16(qf[0][kc], kf, s[0][ss], 0, 0, 0);
          s[1][ss] = __builtin_amdgcn_mfma_f32_16x16x32_bf16(qf[1][kc], kf, s[1][ss], 0, 0, 0);
        }
      }
      __builtin_amdgcn_s_setprio(0);
    }

    // ---- issue K(t+1) into ldsK[cur^1] ----
#pragma unroll
    for (int j = 0; j < 4; ++j) {
      const int r0 = (wid * 4 + j) * 4;
      const int row = r0 + k_row_in;
      const int cc = k_cc_x ^ (row & 7);
      gload_lds16(&Kh[(size_t)(kvn + row) * D + cc * 8], &ldsK[cur ^ 1][r0 * 128]);
    }

    // ---- softmax(t) ----
    if (active) {
      const bool need_mask = (kv0 + 63 > qb);
      float fs[2][4];
#pragma unroll
      for (int m = 0; m < 2; ++m)
#pragma unroll
        for (int r = 0; r < 4; ++r) {
          float v0 = s[m][0][r], v1 = s[m][1][r], v2 = s[m][2][r], v3 = s[m][3][r];
          if (need_mask) {
            const int qrow = qb + m * 16 + lg * 4 + r;
            v0 = (kv0 + lc <= qrow) ? v0 : -1e30f;
            v1 = (kv0 + 16 + lc <= qrow) ? v1 : -1e30f;
            v2 = (kv0 + 32 + lc <= qrow) ? v2 : -1e30f;
            v3 = (kv0 + 48 + lc <= qrow) ? v3 : -1e30f;
          }
          float mx = fmaxf(fmaxf(v0, v1), fmaxf(v2, v3));
          mx = fmaxf(mx, __shfl_xor(mx, 1));
          mx = fmaxf(mx, __shfl_xor(mx, 2));
          mx = fmaxf(mx, __shfl_xor(mx, 4));
          mx = fmaxf(mx, __shfl_xor(mx, 8));
          const float mnew = fmaxf(m_run[m][r], mx);
          const float f = __expf(m_run[m][r] - mnew);
          m_run[m][r] = mnew;
          v0 = __expf(v0 - mnew); v1 = __expf(v1 - mnew);
          v2 = __expf(v2 - mnew); v3 = __expf(v3 - mnew);
          float sm = (v0 + v1) + (v2 + v3);
          sm += __shfl_xor(sm, 1);
          sm += __shfl_xor(sm, 2);
          sm += __shfl_xor(sm, 4);
          sm += __shfl_xor(sm, 8);
          l_run[m][r] = l_run[m][r] * f + sm;
          fs[m][r] = f;
          const int prow = m * 16 + lg * 4 + r;
          p_lds[wid][prow][lc] = f2bf(v0);
          p_lds[wid][prow][16 + lc] = f2bf(v1);
          p_lds[wid][prow][32 + lc] = f2bf(v2);
          p_lds[wid][prow][48 + lc] = f2bf(v3);
        }
#pragma unroll
      for (int m = 0; m < 2; ++m)
#pragma unroll
        for (int nt = 0; nt < 8; ++nt)
#pragma unroll
          for (int r = 0; r < 4; ++r) oacc[m][nt][r] *= fs[m][r];
    }

    // ---- barrier 2: V(t) landed (K(t+1) stays in flight), P visible ----
    asm volatile("s_waitcnt vmcnt(4) lgkmcnt(0)" ::: "memory");
    __builtin_amdgcn_s_barrier();
    __builtin_amdgcn_sched_barrier(0);

    // ---- PV(t) ----
    if (active) {
      short8 pf[2][2];
#pragma unroll
      for (int m = 0; m < 2; ++m)
#pragma unroll
        for (int ks = 0; ks < 2; ++ks)
          pf[m][ks] = *(const short8*)&p_lds[wid][m * 16 + lc][ks * 32 + lg * 8];
      __builtin_amdgcn_s_setprio(1);
#pragma unroll
      for (int nt = 0; nt < 8; ++nt) {
        const int row = nt * 16 + lc;
#pragma unroll
        for (int ks = 0; ks < 2; ++ks) {
          const int p = (ks * 4 + lg) ^ (lc & 7);
          short8 vf = *(const short8*)&ldsV[row * 64 + p * 8];
          oacc[0][nt] = __builtin_amdgcn_mfma_f32_16x16x32_bf16(pf[0][ks], vf, oacc[0][nt], 0, 0, 0);
          oacc[1][nt] = __builtin_amdgcn_mfma_f32_16x16x32_bf16(pf[1][ks], vf, oacc[1][nt], 0, 0, 0);
        }
      }
      __builtin_amdgcn_s_setprio(0);
    }

    // ---- barrier 3: all waves done reading ldsV/p_lds ----
    asm volatile("s_waitcnt lgkmcnt(0)" ::: "memory");
    __builtin_amdgcn_s_barrier();
    __builtin_amdgcn_sched_barrier(0);

    // ---- issue V(t+1) into ldsV ----
#pragma unroll
    for (int j = 0; j < 4; ++j) {
      const int r0 = (wid * 4 + j) * 8;
      const int row = r0 + v_row_in;
      const int cc = v_cc_x ^ (row & 7);
      gload_lds16(&Vh[(size_t)row * T + kvn + cc * 8], &ldsV[r0 * 64]);
    }
    cur ^= 1;
  }

#pragma unroll
  for (int m = 0; m < 2; ++m)
#pragma unroll
    for (int r = 0; r < 4; ++r) {
      const int tq = qb + m * 16 + lg * 4 + r;
      const float inv = 1.0f / l_run[m][r];
      unsigned short* yrow = Y + ((size_t)b * T + tq) * C + h * D;
#pragma unroll
      for (int nt = 0; nt < 8; ++nt)
        yrow[nt * 16 + lc] = f2bf(oacc[m][nt][r] * inv);
    }
}

// ---------------- launch ----------------
extern "C" void kernel_launch(void* const* d_in, const int* in_sizes, int n_in,
                              void* d_out, int out_size, void* d_ws, size_t ws_size,
                              hipStream_t stream) {
  const float* x = (const float*)d_in[0];
  const float* wqkv = (const float*)d_in[1];
  const float* wo = (const float*)d_in[2];
  const float* rc = (const float*)d_in[3];
  const float* rs = (const float*)d_in[4];
  float* out = (float*)d_out;
  char* ws = (char*)d_ws;

  unsigned short* xb    = (unsigned short*)(ws + 0);
  unsigned short* wqkvb = (unsigned short*)(ws + 16777216);
  unsigned short* qkv   = (unsigned short*)(ws + 41943040);
  unsigned short* Qr    = (unsigned short*)(ws + 92274688);
  unsigned short* Kr    = (unsigned short*)(ws + 109051904);
  unsigned short* Vt  = xb;
  unsigned short* Yb  = qkv;
  unsigned short* wob = wqkvb;

  convert_bf16<<<8192, 256, 0, stream>>>(x, xb, Bdim * T * C);
  convert_bf16<<<12288, 256, 0, stream>>>(wqkv, wqkvb, CQ * C);
  gemm_bt<1><<<dim3(CQ / 128, (Bdim * T) / 128), 256, 0, stream>>>(xb, wqkvb, (void*)qkv,
                                                                   Bdim * T, CQ, C);
  rope_kernel<<<(Bdim * T * H * 64) / 256, 256, 0, stream>>>(qkv, rc, rs, Qr, Kr);
  transpose_v<<<dim3(T / 64, D / 64, Bdim * H), 256, 0, stream>>>(qkv, Vt);
  convert_bf16<<<4096, 256, 0, stream>>>(wo, wob, C * C);
  flash_attn<<<dim3(T / 128, Bdim * H), 256, 0, stream>>>(Qr, Kr, Vt, Yb);
  gemm_bt<0><<<dim3(C / 128, (Bdim * T) / 128), 256, 0, stream>>>(Yb, wob, (void*)out,
                                                                  Bdim * T, C, C);
}

// Round 4
// 371.065 us; speedup vs baseline: 1.0457x; 1.0457x over previous
//
#include <hip/hip_runtime.h>
#include <cstdint>
#include <cstddef>

#define DEVI __device__ __forceinline__

typedef __attribute__((ext_vector_type(8))) short short8;
typedef __attribute__((ext_vector_type(4))) float f32x4;

static constexpr int Bdim = 2, T = 2048, C = 2048, H = 16, D = 128;
static constexpr int CQ = 3 * C; // 6144

DEVI unsigned short f2bf(float f) {
  unsigned int u = __float_as_uint(f);
  u = (u + 0x7fffu + ((u >> 16) & 1u)) >> 16; // RNE
  return (unsigned short)u;
}
DEVI float bf2f(unsigned int u) { return __uint_as_float(u << 16); }

DEVI void gload_lds16(const void* g, void* l) {
  __builtin_amdgcn_global_load_lds((const __attribute__((address_space(1))) void*)g,
                                   (__attribute__((address_space(3))) void*)l, 16, 0, 0);
}

// ---------------- f32 -> bf16 convert (4 elems/thread) ----------------
__global__ __launch_bounds__(256) void convert_bf16(const float* __restrict__ src,
                                                    unsigned short* __restrict__ dst, int n) {
  const int i = (blockIdx.x * 256 + threadIdx.x) * 4;
  if (i >= n) return;
  float4 v = *(const float4*)&src[i];
  uint2 o;
  o.x = (unsigned)f2bf(v.x) | ((unsigned)f2bf(v.y) << 16);
  o.y = (unsigned)f2bf(v.z) | ((unsigned)f2bf(v.w) << 16);
  *(uint2*)&dst[i] = o;
}

// ---------------- bf16 GEMM, B^T input ----------------
template <int OUT_BF16>
__global__ __launch_bounds__(256) void gemm_bt(const unsigned short* __restrict__ A,
                                               const unsigned short* __restrict__ Bm,
                                               void* __restrict__ outp,
                                               int M, int N, int Kd) {
  __shared__ __align__(16) unsigned short lds_a[128 * 32];
  __shared__ __align__(16) unsigned short lds_b[128 * 32];
  const int tid = threadIdx.x;
  const int wid = tid >> 6, lane = tid & 63;
  const int lg = lane >> 4, lc = lane & 15;
  const int m0 = blockIdx.y * 128, n0 = blockIdx.x * 128;
  const int wr = (wid >> 1) * 64, wc = (wid & 1) * 64;
  const int srow = lane >> 2;
  const int scol = (lane & 3) * 8;

  f32x4 acc[4][4] = {};

  for (int k0 = 0; k0 < Kd; k0 += 32) {
    __syncthreads();
#pragma unroll
    for (int i = 0; i < 2; ++i) {
      const int c = wid * 2 + i;
      const int row = c * 16 + srow;
      gload_lds16(&A[(size_t)(m0 + row) * Kd + k0 + scol], &lds_a[c * 512]);
      gload_lds16(&Bm[(size_t)(n0 + row) * Kd + k0 + scol], &lds_b[c * 512]);
    }
    __syncthreads();
    short8 af[4], bf[4];
#pragma unroll
    for (int m = 0; m < 4; ++m)
      af[m] = *(const short8*)&lds_a[(wr + m * 16 + lc) * 32 + lg * 8];
#pragma unroll
    for (int n = 0; n < 4; ++n)
      bf[n] = *(const short8*)&lds_b[(wc + n * 16 + lc) * 32 + lg * 8];
#pragma unroll
    for (int m = 0; m < 4; ++m)
#pragma unroll
      for (int n = 0; n < 4; ++n)
        acc[m][n] = __builtin_amdgcn_mfma_f32_16x16x32_bf16(af[m], bf[n], acc[m][n], 0, 0, 0);
  }

#pragma unroll
  for (int m = 0; m < 4; ++m)
#pragma unroll
    for (int n = 0; n < 4; ++n)
#pragma unroll
      for (int r = 0; r < 4; ++r) {
        const int row = m0 + wr + m * 16 + lg * 4 + r;
        const int col = n0 + wc + n * 16 + lc;
        const float v = acc[m][n][r];
        if (OUT_BF16)
          ((unsigned short*)outp)[(size_t)row * N + col] = f2bf(v);
        else
          ((float*)outp)[(size_t)row * N + col] = v;
      }
}

// ---------------- RoPE ----------------
__global__ __launch_bounds__(256) void rope_kernel(const unsigned short* __restrict__ qkv,
                                                   const float* __restrict__ cosb,
                                                   const float* __restrict__ sinb,
                                                   unsigned short* __restrict__ Qr,
                                                   unsigned short* __restrict__ Kr) {
  const int idx = blockIdx.x * 256 + threadIdx.x;
  const int i = idx & 63;
  const int h = (idx >> 6) & (H - 1);
  const int tg = idx >> 10;
  const int t = tg & (T - 1);
  const int b = tg >> 11;
  const float c = cosb[t * 64 + i], s = sinb[t * 64 + i];
  const unsigned short* row = qkv + (size_t)tg * CQ;
  const unsigned int q = *(const unsigned int*)&row[h * D + 2 * i];
  const unsigned int k = *(const unsigned int*)&row[C + h * D + 2 * i];
  const float q0 = bf2f(q & 0xffffu), q1 = bf2f(q >> 16);
  const float k0 = bf2f(k & 0xffffu), k1 = bf2f(k >> 16);
  const float SC = 0.08838834764831845f; // 1/sqrt(128)
  const float q0r = (q0 * c - q1 * s) * SC, q1r = (q0 * s + q1 * c) * SC;
  const float k0r = k0 * c - k1 * s, k1r = k0 * s + k1 * c;
  const size_t off = ((size_t)(b * H + h) * T + t) * D + 2 * i;
  *(unsigned int*)&Qr[off] = (unsigned)f2bf(q0r) | ((unsigned)f2bf(q1r) << 16);
  *(unsigned int*)&Kr[off] = (unsigned)f2bf(k0r) | ((unsigned)f2bf(k1r) << 16);
}

// ---------------- V transpose ----------------
__global__ __launch_bounds__(256) void transpose_v(const unsigned short* __restrict__ qkv,
                                                   unsigned short* __restrict__ Vt) {
  __shared__ unsigned short tile[64][65];
  const int bh = blockIdx.z, b = bh >> 4, h = bh & (H - 1);
  const int t0 = blockIdx.x * 64, d0 = blockIdx.y * 64;
  const int tx = threadIdx.x & 63, ty = threadIdx.x >> 6;
#pragma unroll
  for (int rr = 0; rr < 64; rr += 4)
    tile[rr + ty][tx] = qkv[(size_t)(b * T + t0 + rr + ty) * CQ + 2 * C + h * D + d0 + tx];
  __syncthreads();
#pragma unroll
  for (int rr = 0; rr < 64; rr += 4)
    Vt[((size_t)bh * D + d0 + rr + ty) * T + t0 + tx] = tile[tx][rr + ty];
}

// ---------------- causal flash attention ----------------
// grid (T/64, B*H) heavy-first; 4 waves, wave owns 16 q rows (m=1).
// KV tile = 64 staged in LDS (swizzled source). Every wave active every tile;
// only the diagonal tile masks. Per-lane partial l_run, reduced once at end;
// rescale skipped exactly when running max didn't grow.
__global__ __launch_bounds__(256, 3) void flash_attn(const unsigned short* __restrict__ Q,
                                                     const unsigned short* __restrict__ K,
                                                     const unsigned short* __restrict__ Vt,
                                                     unsigned short* __restrict__ Y) {
  __shared__ __align__(16) unsigned short ldsK[64 * 128];  // 16 KB
  __shared__ __align__(16) unsigned short ldsV[128 * 64];  // 16 KB
  __shared__ __align__(16) unsigned short p_lds[4][16][72];  // 9 KB

  const int bh = blockIdx.y;
  const int qt = gridDim.x - 1 - blockIdx.x;  // heavy blocks first (LPT)
  const int wid = threadIdx.x >> 6;
  const int lane = threadIdx.x & 63;
  const int lg = lane >> 4, lc = lane & 15;
  const int b = bh >> 4, h = bh & (H - 1);
  const int qb = qt * 64 + wid * 16;

  const unsigned short* Qh = Q + (size_t)bh * T * D;
  const unsigned short* Kh = K + (size_t)bh * T * D;
  const unsigned short* Vh = Vt + (size_t)bh * D * T;

  short8 qf[4];
#pragma unroll
  for (int kc = 0; kc < 4; ++kc)
    qf[kc] = *(const short8*)&Qh[(size_t)(qb + lc) * D + kc * 32 + lg * 8];

  f32x4 oacc[8] = {};
  float m_run[4], l_run[4];
#pragma unroll
  for (int r = 0; r < 4; ++r) { m_run[r] = -1e30f; l_run[r] = 0.f; }

  for (int t = 0; t <= qt; ++t) {
    const int kv0 = t * 64;
    __syncthreads();  // previous tile's readers done
    // stage K: 16 wave-insts of 4 rows each; this wave does 4
#pragma unroll
    for (int j = 0; j < 4; ++j) {
      const int r0 = (wid * 4 + j) * 4;
      const int row = r0 + (lane >> 4);
      const int cc = (lane & 15) ^ (row & 7);  // pre-swizzled source chunk
      gload_lds16(&Kh[(size_t)(kv0 + row) * D + cc * 8], &ldsK[r0 * 128]);
    }
    // stage V^T: 16 wave-insts of 8 rows each; this wave does 4
#pragma unroll
    for (int j = 0; j < 4; ++j) {
      const int r0 = (wid * 4 + j) * 8;
      const int row = r0 + (lane >> 3);
      const int cc = (lane & 7) ^ (row & 7);
      gload_lds16(&Vh[(size_t)row * T + kv0 + cc * 8], &ldsV[r0 * 64]);
    }
    __syncthreads();  // drain -> tile ready

    // ---- QK^T ----
    f32x4 s[4] = {};
    __builtin_amdgcn_s_setprio(1);
#pragma unroll
    for (int ss = 0; ss < 4; ++ss) {
      const int row = ss * 16 + lc;
#pragma unroll
      for (int kc = 0; kc < 4; ++kc) {
        const int p = (kc * 4 + lg) ^ (lc & 7);
        short8 kf = *(const short8*)&ldsK[row * 128 + p * 8];
        s[ss] = __builtin_amdgcn_mfma_f32_16x16x32_bf16(qf[kc], kf, s[ss], 0, 0, 0);
      }
    }
    __builtin_amdgcn_s_setprio(0);

    // ---- softmax: max-only cross-lane; per-lane partial sums ----
    const bool need_mask = (t == qt);
    float vv[4][4], mx4[4];
#pragma unroll
    for (int r = 0; r < 4; ++r) {
      float a0 = s[0][r], a1 = s[1][r], a2 = s[2][r], a3 = s[3][r];
      if (need_mask) {
        const int qrow = qb + lg * 4 + r;
        a0 = (kv0 + lc <= qrow) ? a0 : -1e30f;
        a1 = (kv0 + 16 + lc <= qrow) ? a1 : -1e30f;
        a2 = (kv0 + 32 + lc <= qrow) ? a2 : -1e30f;
        a3 = (kv0 + 48 + lc <= qrow) ? a3 : -1e30f;
      }
      vv[r][0] = a0; vv[r][1] = a1; vv[r][2] = a2; vv[r][3] = a3;
      float mx = fmaxf(fmaxf(a0, a1), fmaxf(a2, a3));
      mx = fmaxf(mx, __shfl_xor(mx, 1));
      mx = fmaxf(mx, __shfl_xor(mx, 2));
      mx = fmaxf(mx, __shfl_xor(mx, 4));
      mx = fmaxf(mx, __shfl_xor(mx, 8));
      mx4[r] = mx;
    }
    const bool grew = (mx4[0] > m_run[0]) | (mx4[1] > m_run[1]) |
                      (mx4[2] > m_run[2]) | (mx4[3] > m_run[3]);
    if (__any(grew)) {  // exact skip: f==1 when max unchanged
      float fs[4];
#pragma unroll
      for (int r = 0; r < 4; ++r) {
        const float mnew = fmaxf(m_run[r], mx4[r]);
        fs[r] = __expf(m_run[r] - mnew);
        m_run[r] = mnew;
        l_run[r] *= fs[r];
      }
#pragma unroll
      for (int nt = 0; nt < 8; ++nt)
#pragma unroll
        for (int r = 0; r < 4; ++r) oacc[nt][r] *= fs[r];
    }
#pragma unroll
    for (int r = 0; r < 4; ++r) {
      const float e0 = __expf(vv[r][0] - m_run[r]);
      const float e1 = __expf(vv[r][1] - m_run[r]);
      const float e2 = __expf(vv[r][2] - m_run[r]);
      const float e3 = __expf(vv[r][3] - m_run[r]);
      l_run[r] += (e0 + e1) + (e2 + e3);  // per-lane partial; reduced at end
      const int prow = lg * 4 + r;
      p_lds[wid][prow][lc] = f2bf(e0);
      p_lds[wid][prow][16 + lc] = f2bf(e1);
      p_lds[wid][prow][32 + lc] = f2bf(e2);
      p_lds[wid][prow][48 + lc] = f2bf(e3);
    }

    // ---- PV ----
    short8 pf[2];
#pragma unroll
    for (int ks = 0; ks < 2; ++ks)
      pf[ks] = *(const short8*)&p_lds[wid][lc][ks * 32 + lg * 8];
    __builtin_amdgcn_s_setprio(1);
#pragma unroll
    for (int nt = 0; nt < 8; ++nt) {
      const int row = nt * 16 + lc;
#pragma unroll
      for (int ks = 0; ks < 2; ++ks) {
        const int p = (ks * 4 + lg) ^ (lc & 7);
        short8 vf = *(const short8*)&ldsV[row * 64 + p * 8];
        oacc[nt] = __builtin_amdgcn_mfma_f32_16x16x32_bf16(pf[ks], vf, oacc[nt], 0, 0, 0);
      }
    }
    __builtin_amdgcn_s_setprio(0);
  }

  // final cross-lane reduction of l, then scale + store
#pragma unroll
  for (int r = 0; r < 4; ++r) {
    float l = l_run[r];
    l += __shfl_xor(l, 1);
    l += __shfl_xor(l, 2);
    l += __shfl_xor(l, 4);
    l += __shfl_xor(l, 8);
    const float inv = 1.0f / l;
    const int tq = qb + lg * 4 + r;
    unsigned short* yrow = Y + ((size_t)b * T + tq) * C + h * D;
#pragma unroll
    for (int nt = 0; nt < 8; ++nt)
      yrow[nt * 16 + lc] = f2bf(oacc[nt][r] * inv);
  }
}

// ---------------- launch ----------------
extern "C" void kernel_launch(void* const* d_in, const int* in_sizes, int n_in,
                              void* d_out, int out_size, void* d_ws, size_t ws_size,
                              hipStream_t stream) {
  const float* x = (const float*)d_in[0];
  const float* wqkv = (const float*)d_in[1];
  const float* wo = (const float*)d_in[2];
  const float* rc = (const float*)d_in[3];
  const float* rs = (const float*)d_in[4];
  float* out = (float*)d_out;
  char* ws = (char*)d_ws;

  unsigned short* xb    = (unsigned short*)(ws + 0);
  unsigned short* wqkvb = (unsigned short*)(ws + 16777216);
  unsigned short* qkv   = (unsigned short*)(ws + 41943040);
  unsigned short* Qr    = (unsigned short*)(ws + 92274688);
  unsigned short* Kr    = (unsigned short*)(ws + 109051904);
  unsigned short* Vt  = xb;
  unsigned short* Yb  = qkv;
  unsigned short* wob = wqkvb;

  convert_bf16<<<8192, 256, 0, stream>>>(x, xb, Bdim * T * C);
  convert_bf16<<<12288, 256, 0, stream>>>(wqkv, wqkvb, CQ * C);
  gemm_bt<1><<<dim3(CQ / 128, (Bdim * T) / 128), 256, 0, stream>>>(xb, wqkvb, (void*)qkv,
                                                                   Bdim * T, CQ, C);
  rope_kernel<<<(Bdim * T * H * 64) / 256, 256, 0, stream>>>(qkv, rc, rs, Qr, Kr);
  transpose_v<<<dim3(T / 64, D / 64, Bdim * H), 256, 0, stream>>>(qkv, Vt);
  convert_bf16<<<4096, 256, 0, stream>>>(wo, wob, C * C);
  flash_attn<<<dim3(T / 64, Bdim * H), 256, 0, stream>>>(Qr, Kr, Vt, Yb);
  gemm_bt<0><<<dim3(C / 128, (Bdim * T) / 128), 256, 0, stream>>>(Yb, wob, (void*)out,
                                                                  Bdim * T, C, C);
}